// Round 9
// baseline (283.687 us; speedup 1.0000x reference)
//
#include <hip/hip_runtime.h>
#include <math.h>

#define N_NODES 512
#define DIM 128
#define NANCH 192
#define G3 384           // 3*DIM gate width
#define FOUT 47
#define DBINS 21

__device__ __forceinline__ float fast_sigmoid(float x) {
    return __builtin_amdgcn_rcpf(1.f + __expf(-x));
}
__device__ __forceinline__ float fast_tanh(float x) {
    return 1.f - 2.f * __builtin_amdgcn_rcpf(1.f + __expf(2.f * x));
}

// ============ Kernel 1: fused [xW GEMM | membership + abnormal + H=1 BiGRU] ============
// blocks 0..191   : xW = x @ Wih^T + bih  (sd = blk>>5, node-group = blk&31)
// blocks 192..383 : per-anchor membership list + abnormal scores + scalar BiGRU
__global__ __launch_bounds__(384) void prep_kernel(
    const float* __restrict__ emb, const float* __restrict__ tpin,
    const float* __restrict__ Wih, const float* __restrict__ bih,
    const float* __restrict__ alp, const float* __restrict__ anchors,
    const float* __restrict__ npred, const float* __restrict__ skern,
    const float* __restrict__ aWih, const float* __restrict__ aWhh,
    const float* __restrict__ abih, const float* __restrict__ abhh,
    float* __restrict__ xW, int* __restrict__ members,
    int* __restrict__ lens, float* __restrict__ abn_res)
{
    int blk = blockIdx.x;
    int tid = threadIdx.x;     // 0..383
    if (blk < 192) {
        int sd = blk >> 5;         // 0..5
        int ng = blk & 31;         // 0..31
        __shared__ __align__(16) float xs[16][DIM];
        for (int idx = tid; idx < 16 * DIM; idx += 384) {
            int m = idx >> 7, k = idx & 127;
            int node = ng * 16 + m;
            float tv = tpin[node];
            float freq = 10.f * (float)k / 127.f;
            xs[m][k] = emb[node * DIM + k] + 0.05f * __sinf(tv * freq);
        }
        __syncthreads();
        float acc[16];
        float b = bih[sd * G3 + tid];
        #pragma unroll
        for (int m = 0; m < 16; ++m) acc[m] = b;
        const float* wrow = Wih + ((size_t)sd * G3 + tid) * DIM;
        for (int k = 0; k < DIM; k += 4) {
            float4 w4 = *(const float4*)(wrow + k);
            #pragma unroll
            for (int m = 0; m < 16; ++m) {
                float4 xv = *(const float4*)&xs[m][k];   // wave-uniform b128 broadcast
                acc[m] = fmaf(w4.x, xv.x, acc[m]);
                acc[m] = fmaf(w4.y, xv.y, acc[m]);
                acc[m] = fmaf(w4.z, xv.z, acc[m]);
                acc[m] = fmaf(w4.w, xv.w, acc[m]);
            }
        }
        #pragma unroll
        for (int m = 0; m < 16; ++m)
            xW[((size_t)sd * N_NODES + ng * 16 + m) * G3 + tid] = acc[m];
    } else {
        int a = blk - 192;
        float al = alp[0];
        float s0 = anchors[a * 2 + 0];
        float e0 = anchors[a * 2 + 1];
        __shared__ int memloc[N_NODES];
        __shared__ float abn_lds[N_NODES];
        for (int node = tid; node < N_NODES; node += 384) {
            float sc[5];
            #pragma unroll
            for (int ch = 0; ch < 5; ++ch) {
                float acc = 0.f;
                #pragma unroll
                for (int k = 0; k < 5; ++k) {
                    int r = node + k - 2;
                    if (r >= 0 && r < N_NODES) acc += skern[k] * npred[r * 5 + ch];
                }
                sc[ch] = acc;
            }
            float m = sc[0];
            #pragma unroll
            for (int ch = 1; ch < 5; ++ch) m = fmaxf(m, sc[ch]);
            float sum = 0.f;
            #pragma unroll
            for (int ch = 0; ch < 5; ++ch) sum += __expf(sc[ch] - m);
            abn_lds[node] = __expf(sc[0] - m) / sum;
        }
        __syncthreads();
        if (tid < 64) {
            int lane = tid;
            int count = 0;
            for (int c = 0; c < N_NODES / 64; ++c) {
                int node = c * 64 + lane;
                float tp = tpin[node] * al;
                bool in = (tp >= s0) && (tp <= e0);
                unsigned long long m = __ballot(in);
                if (in) {
                    int pos = count + __popcll(m & ((1ull << lane) - 1ull));
                    members[a * N_NODES + pos] = node;
                    memloc[pos] = node;
                }
                count += __popcll(m);
            }
            if (lane == 0) lens[a] = count;
            int sc3 = a >> 6;
            float h = 0.f;
            if (lane < 2) {
                int sd = sc3 * 2 + lane;
                float wi0 = aWih[sd*3+0], wi1 = aWih[sd*3+1], wi2 = aWih[sd*3+2];
                float wh0 = aWhh[sd*3+0], wh1 = aWhh[sd*3+1], wh2 = aWhh[sd*3+2];
                float bi0 = abih[sd*3+0], bi1 = abih[sd*3+1], bi2 = abih[sd*3+2];
                float bh0 = abhh[sd*3+0], bh1 = abhh[sd*3+1], bh2 = abhh[sd*3+2];
                for (int t = 0; t < count; ++t) {
                    int idx = lane ? (count - 1 - t) : t;
                    float xv = abn_lds[memloc[idx]];
                    float r = fast_sigmoid(fmaf(wi0, xv, bi0) + fmaf(wh0, h, bh0));
                    float z = fast_sigmoid(fmaf(wi1, xv, bi1) + fmaf(wh1, h, bh1));
                    float nv = fast_tanh(fmaf(wi2, xv, bi2) + r * fmaf(wh2, h, bh2));
                    h = (1.f - z) * nv + z * h;
                }
            }
            float hb = __shfl(h, 1);
            if (lane == 0) abn_res[a] = 0.5f * (h + hb);
        }
    }
}

// ============ Kernel 2: H=128 GRU — anchor-PAIR blocks share each weight reload ============
// grid: 192 blocks = (scale, dir, anchor-pair) -> 1 block/CU, single scheduling round.
// 512 threads: thread = (j = t>>2 owned h element, s = t&3 32-wide K slice), serving
// BOTH anchors of the pair: each rematerialized Whh float is used twice back-to-back,
// halving the weight-reload bandwidth per anchor-step (R8 analysis: that traffic is the
// bottleneck). At 1 block/CU the VGPR-64 occupancy cliff is irrelevant (<=128 free).
// Tail steps (tt >= len_X) carry h forward via cndmask, matching reference masking.
__global__ __launch_bounds__(512, 2) void gru_feat_kernel(
    const float* __restrict__ xW, const float* __restrict__ Whh,
    const float* __restrict__ bhh, const int* __restrict__ members,
    const int* __restrict__ lens, float* __restrict__ feat_out)
{
    int b = blockIdx.x;        // 0..191
    int pr = b >> 1;           // pair 0..95
    int dir = b & 1;
    int aA = pr * 2, aB = aA + 1;
    int s3 = aA >> 6;          // scale (pairs never straddle scales: 64 per scale)
    int sd = s3 * 2 + dir;
    int t0 = threadIdx.x;      // 0..511
    int j  = t0 >> 2;          // 0..127 : owned h element
    int s  = t0 & 3;           // 0..3   : 32-wide K slice

    // h ping-pong for both anchors. Slice bases (anc*144 + s*36 words) mod 32 =
    // {0,4,8,12,16,20,24,28}: the 8 wave-level b128 addresses tile all 32 banks.
    __shared__ __align__(16) float hbuf[2][2][4][36];
    __shared__ int memA[N_NODES], memB[N_NODES];

    int lenA = lens[aA], lenB = lens[aB];
    int len = max(lenA, lenB);
    for (int i = t0; i < 2 * 2 * 4 * 36; i += 512) ((float*)hbuf)[i] = 0.f;
    for (int i = t0; i < lenA; i += 512) memA[i] = members[aA * N_NODES + i];
    for (int i = t0; i < lenB; i += 512) memB[i] = members[aB * N_NODES + i];

    // this thread's Whh slices (compiler remats the loads; each is now dual-use)
    float wr[32], wz[32], wn[32];
    {
        const float* base = Whh + ((size_t)sd * G3) * DIM;
        const float* pr_ = base + (size_t)(j        ) * DIM + s * 32;
        const float* pz_ = base + (size_t)(j + DIM  ) * DIM + s * 32;
        const float* pn_ = base + (size_t)(j + 2*DIM) * DIM + s * 32;
        #pragma unroll
        for (int q = 0; q < 8; ++q) {
            float4 v = *(const float4*)(pr_ + 4 * q);
            wr[4*q+0]=v.x; wr[4*q+1]=v.y; wr[4*q+2]=v.z; wr[4*q+3]=v.w;
        }
        #pragma unroll
        for (int q = 0; q < 8; ++q) {
            float4 v = *(const float4*)(pz_ + 4 * q);
            wz[4*q+0]=v.x; wz[4*q+1]=v.y; wz[4*q+2]=v.z; wz[4*q+3]=v.w;
        }
        #pragma unroll
        for (int q = 0; q < 8; ++q) {
            float4 v = *(const float4*)(pn_ + 4 * q);
            wn[4*q+0]=v.x; wn[4*q+1]=v.y; wn[4*q+2]=v.z; wn[4*q+3]=v.w;
        }
    }
    float bhr = bhh[sd * G3 + j];
    float bhz = bhh[sd * G3 + DIM + j];
    float bhn = bhh[sd * G3 + 2 * DIM + j];
    const float* xWp = xW + (size_t)sd * N_NODES * G3;
    __syncthreads();

    // prefetch gi for step 0 (guard len==0: poisoned members must not be read)
    int nA = (lenA > 0) ? memA[dir ? (lenA - 1) : 0] : 0;
    int nB = (lenB > 0) ? memB[dir ? (lenB - 1) : 0] : 0;
    float grA = xWp[(size_t)nA * G3 + j];
    float gzA = xWp[(size_t)nA * G3 + DIM + j];
    float gnA = xWp[(size_t)nA * G3 + 2 * DIM + j];
    float grB = xWp[(size_t)nB * G3 + j];
    float gzB = xWp[(size_t)nB * G3 + DIM + j];
    float gnB = xWp[(size_t)nB * G3 + 2 * DIM + j];

    int cur = 0;
    for (int tt = 0; tt < len; ++tt) {
        // prefetch next step's gi (block-uniform branches: scalar, no divergence)
        float grA_n = 0.f, gzA_n = 0.f, gnA_n = 0.f;
        float grB_n = 0.f, gzB_n = 0.f, gnB_n = 0.f;
        int t1 = tt + 1;
        if (t1 < lenA) {
            int nn = memA[dir ? (lenA - 1 - t1) : t1];
            grA_n = xWp[(size_t)nn * G3 + j];
            gzA_n = xWp[(size_t)nn * G3 + DIM + j];
            gnA_n = xWp[(size_t)nn * G3 + 2 * DIM + j];
        }
        if (t1 < lenB) {
            int nn = memB[dir ? (lenB - 1 - t1) : t1];
            grB_n = xWp[(size_t)nn * G3 + j];
            gzB_n = xWp[(size_t)nn * G3 + DIM + j];
            gnB_n = xWp[(size_t)nn * G3 + 2 * DIM + j];
        }
        // dual dot products sharing each weight value
        float arA = 0.f, azA = 0.f, anA = 0.f;
        float arB = 0.f, azB = 0.f, anB = 0.f;
        const float4* hpA = (const float4*)(&hbuf[cur][0][s][0]);
        const float4* hpB = (const float4*)(&hbuf[cur][1][s][0]);
        #pragma unroll
        for (int q = 0; q < 8; ++q) {
            float4 hA = hpA[q];
            float4 hB = hpB[q];
            arA = fmaf(wr[4*q+0], hA.x, arA); arB = fmaf(wr[4*q+0], hB.x, arB);
            arA = fmaf(wr[4*q+1], hA.y, arA); arB = fmaf(wr[4*q+1], hB.y, arB);
            arA = fmaf(wr[4*q+2], hA.z, arA); arB = fmaf(wr[4*q+2], hB.z, arB);
            arA = fmaf(wr[4*q+3], hA.w, arA); arB = fmaf(wr[4*q+3], hB.w, arB);
            azA = fmaf(wz[4*q+0], hA.x, azA); azB = fmaf(wz[4*q+0], hB.x, azB);
            azA = fmaf(wz[4*q+1], hA.y, azA); azB = fmaf(wz[4*q+1], hB.y, azB);
            azA = fmaf(wz[4*q+2], hA.z, azA); azB = fmaf(wz[4*q+2], hB.z, azB);
            azA = fmaf(wz[4*q+3], hA.w, azA); azB = fmaf(wz[4*q+3], hB.w, azB);
            anA = fmaf(wn[4*q+0], hA.x, anA); anB = fmaf(wn[4*q+0], hB.x, anB);
            anA = fmaf(wn[4*q+1], hA.y, anA); anB = fmaf(wn[4*q+1], hB.y, anB);
            anA = fmaf(wn[4*q+2], hA.z, anA); anB = fmaf(wn[4*q+2], hB.z, anB);
            anA = fmaf(wn[4*q+3], hA.w, anA); anB = fmaf(wn[4*q+3], hB.w, anB);
        }
        // quad reductions (lanes 4j..4j+3 adjacent in wave)
        arA += __shfl_xor(arA, 1); arA += __shfl_xor(arA, 2);
        azA += __shfl_xor(azA, 1); azA += __shfl_xor(azA, 2);
        anA += __shfl_xor(anA, 1); anA += __shfl_xor(anA, 2);
        arB += __shfl_xor(arB, 1); arB += __shfl_xor(arB, 2);
        azB += __shfl_xor(azB, 1); azB += __shfl_xor(azB, 2);
        anB += __shfl_xor(anB, 1); anB += __shfl_xor(anB, 2);

        float rA  = fast_sigmoid(grA + arA + bhr);
        float zA  = fast_sigmoid(gzA + azA + bhz);
        float nvA = fast_tanh(gnA + rA * (anA + bhn));
        float hjA = hbuf[cur][0][j >> 5][j & 31];
        float hA2 = (tt < lenA) ? ((1.f - zA) * nvA + zA * hjA) : hjA;

        float rB  = fast_sigmoid(grB + arB + bhr);
        float zB  = fast_sigmoid(gzB + azB + bhz);
        float nvB = fast_tanh(gnB + rB * (anB + bhn));
        float hjB = hbuf[cur][1][j >> 5][j & 31];
        float hB2 = (tt < lenB) ? ((1.f - zB) * nvB + zB * hjB) : hjB;

        if (s == 0) {
            hbuf[cur ^ 1][0][j >> 5][j & 31] = hA2;
            hbuf[cur ^ 1][1][j >> 5][j & 31] = hB2;
        }
        __syncthreads();
        cur ^= 1;
        grA = grA_n; gzA = gzA_n; gnA = gnA_n;
        grB = grB_n; gzB = gzB_n; gnB = gnB_n;
    }
    if (s == 0) {
        feat_out[aA * 256 + dir * DIM + j] = hbuf[cur][0][j >> 5][j & 31];
        feat_out[aB * 256 + dir * DIM + j] = hbuf[cur][1][j >> 5][j & 31];
    }
}

// ============ Kernel 3: per-anchor MLP head + boundary refinement ============
__global__ __launch_bounds__(256) void head_kernel(
    const float* __restrict__ feat, const float* __restrict__ abn_res,
    const float* __restrict__ anchors, const float* __restrict__ alp,
    const float* __restrict__ W1, const float* __restrict__ b1,
    const float* __restrict__ W2, const float* __restrict__ b2,
    const float* __restrict__ W3, const float* __restrict__ b3,
    const float* __restrict__ sw, const float* __restrict__ ew,
    float* __restrict__ out)
{
    int a = blockIdx.x;
    int tid = threadIdx.x;   // 0..255
    int s = a >> 6;
    __shared__ float sf[260];
    __shared__ float h1[256];
    __shared__ float h2[256];
    __shared__ float o[FOUT];
    float al = alp[0];
    float st = anchors[a * 2 + 0];
    float en = anchors[a * 2 + 1];
    sf[tid] = feat[a * 256 + tid];
    if (tid == 0) {
        sf[256] = abn_res[a];
        sf[257] = (st + en) * 0.5f / al;
        sf[258] = (en - st) / al;
    }
    __syncthreads();

    const float* w1 = W1 + (size_t)s * 259 * 256;
    float acc = b1[s * 256 + tid];
    for (int jj = 0; jj < 259; ++jj) acc = fmaf(sf[jj], w1[jj * 256 + tid], acc);
    h1[tid] = fmaxf(acc, 0.f);
    __syncthreads();

    const float* w2 = W2 + (size_t)s * 256 * 256;
    acc = b2[s * 256 + tid];
    for (int jj = 0; jj < 256; ++jj) acc = fmaf(h1[jj], w2[jj * 256 + tid], acc);
    h2[tid] = fmaxf(acc, 0.f);
    __syncthreads();

    if (tid < FOUT) {
        const float* w3 = W3 + (size_t)s * 256 * FOUT;
        acc = b3[s * FOUT + tid];
        for (int jj = 0; jj < 256; ++jj) acc = fmaf(h2[jj], w3[jj * FOUT + tid], acc);
        o[tid] = acc;
    }
    __syncthreads();

    if (tid < 2) {   // tid 0: start offset, tid 1: end offset
        const float* lw = (tid == 0) ? (sw + s * DBINS) : (ew + s * DBINS);
        const float* sl = o + tid * DBINS;
        float m = sl[0];
        for (int jj = 1; jj < DBINS; ++jj) m = fmaxf(m, sl[jj]);
        float sum = 0.f, dot = 0.f;
        for (int jj = 0; jj < DBINS; ++jj) {
            float e = __expf(sl[jj] - m);
            sum += e;
            dot = fmaf(e, lw[jj], dot);
        }
        float off = dot / sum;
        float base = (tid == 0) ? st : en;
        out[a * 2 + tid] = fminf(fmaxf(base + off, 0.f), al);
    }
    if (tid == 42) out[2 * NANCH + a] = o[42];                           // conf
    if (tid >= 43 && tid < FOUT) out[3 * NANCH + a * 4 + (tid - 43)] = o[tid]; // cls
}

extern "C" void kernel_launch(void* const* d_in, const int* in_sizes, int n_in,
                              void* d_out, int out_size, void* d_ws, size_t ws_size,
                              hipStream_t stream) {
    const float* emb   = (const float*)d_in[0];
    const float* tpin  = (const float*)d_in[1];
    const float* npred = (const float*)d_in[2];
    const float* alp   = (const float*)d_in[3];
    const float* anch  = (const float*)d_in[4];
    const float* skern = (const float*)d_in[5];
    const float* fWih  = (const float*)d_in[6];
    const float* fWhh  = (const float*)d_in[7];
    const float* fbih  = (const float*)d_in[8];
    const float* fbhh  = (const float*)d_in[9];
    const float* aWih  = (const float*)d_in[10];
    const float* aWhh  = (const float*)d_in[11];
    const float* abih  = (const float*)d_in[12];
    const float* abhh  = (const float*)d_in[13];
    const float* sw    = (const float*)d_in[14];
    const float* ew    = (const float*)d_in[15];
    const float* W1    = (const float*)d_in[16];
    const float* b1    = (const float*)d_in[17];
    const float* W2    = (const float*)d_in[18];
    const float* b2    = (const float*)d_in[19];
    const float* W3    = (const float*)d_in[20];
    const float* b3    = (const float*)d_in[21];

    float* ws = (float*)d_ws;
    float* xW       = ws;                      // 6*512*384 = 1179648
    float* abn_res  = ws + 1179648;            // 192 (pad 256)
    float* feat     = ws + 1179904;            // 192*256 = 49152
    int*   members  = (int*)(ws + 1229056);    // 192*512 ints = 98304
    int*   lens     = (int*)(ws + 1327360);    // 192 ints
    float* outp     = (float*)d_out;

    prep_kernel<<<384, 384, 0, stream>>>(emb, tpin, fWih, fbih, alp, anch, npred, skern,
                                         aWih, aWhh, abih, abhh,
                                         xW, members, lens, abn_res);
    gru_feat_kernel<<<NANCH, 512, 0, stream>>>(xW, fWhh, fbhh, members, lens, feat);
    head_kernel<<<NANCH, 256, 0, stream>>>(feat, abn_res, anch, alp,
                                           W1, b1, W2, b2, W3, b3, sw, ew, outp);
}

// Round 10
// 266.910 us; speedup vs baseline: 1.0629x; 1.0629x over previous
//
#include <hip/hip_runtime.h>
#include <math.h>

#define N_NODES 512
#define DIM 128
#define NANCH 192
#define G3 384           // 3*DIM gate width
#define FOUT 47
#define DBINS 21

__device__ __forceinline__ float fast_sigmoid(float x) {
    return __builtin_amdgcn_rcpf(1.f + __expf(-x));
}
__device__ __forceinline__ float fast_tanh(float x) {
    return 1.f - 2.f * __builtin_amdgcn_rcpf(1.f + __expf(2.f * x));
}

// ============ Kernel 1: fused [xW GEMM | membership + abnormal + H=1 BiGRU] ============
// blocks 0..191   : xW = x @ Wih^T + bih  (sd = blk>>5, node-group = blk&31)
// blocks 192..383 : per-anchor membership list + abnormal + scalar BiGRU + flag zero
__global__ __launch_bounds__(384) void prep_kernel(
    const float* __restrict__ emb, const float* __restrict__ tpin,
    const float* __restrict__ Wih, const float* __restrict__ bih,
    const float* __restrict__ alp, const float* __restrict__ anchors,
    const float* __restrict__ npred, const float* __restrict__ skern,
    const float* __restrict__ aWih, const float* __restrict__ aWhh,
    const float* __restrict__ abih, const float* __restrict__ abhh,
    float* __restrict__ xW, int* __restrict__ members,
    int* __restrict__ lens, float* __restrict__ abn_res,
    int* __restrict__ flags)
{
    int blk = blockIdx.x;
    int tid = threadIdx.x;     // 0..383
    if (blk < 192) {
        int sd = blk >> 5;         // 0..5
        int ng = blk & 31;         // 0..31
        __shared__ __align__(16) float xs[16][DIM];
        for (int idx = tid; idx < 16 * DIM; idx += 384) {
            int m = idx >> 7, k = idx & 127;
            int node = ng * 16 + m;
            float tv = tpin[node];
            float freq = 10.f * (float)k / 127.f;
            xs[m][k] = emb[node * DIM + k] + 0.05f * __sinf(tv * freq);
        }
        __syncthreads();
        float acc[16];
        float b = bih[sd * G3 + tid];
        #pragma unroll
        for (int m = 0; m < 16; ++m) acc[m] = b;
        const float* wrow = Wih + ((size_t)sd * G3 + tid) * DIM;
        for (int k = 0; k < DIM; k += 4) {
            float4 w4 = *(const float4*)(wrow + k);
            #pragma unroll
            for (int m = 0; m < 16; ++m) {
                float4 xv = *(const float4*)&xs[m][k];   // wave-uniform b128 broadcast
                acc[m] = fmaf(w4.x, xv.x, acc[m]);
                acc[m] = fmaf(w4.y, xv.y, acc[m]);
                acc[m] = fmaf(w4.z, xv.z, acc[m]);
                acc[m] = fmaf(w4.w, xv.w, acc[m]);
            }
        }
        #pragma unroll
        for (int m = 0; m < 16; ++m)
            xW[((size_t)sd * N_NODES + ng * 16 + m) * G3 + tid] = acc[m];
    } else {
        int a = blk - 192;
        if (tid == 0) flags[a] = 0;    // handshake flag for gru-fused head (ws is poisoned)
        float al = alp[0];
        float s0 = anchors[a * 2 + 0];
        float e0 = anchors[a * 2 + 1];
        __shared__ int memloc[N_NODES];
        __shared__ float abn_lds[N_NODES];
        for (int node = tid; node < N_NODES; node += 384) {
            float sc[5];
            #pragma unroll
            for (int ch = 0; ch < 5; ++ch) {
                float acc = 0.f;
                #pragma unroll
                for (int k = 0; k < 5; ++k) {
                    int r = node + k - 2;
                    if (r >= 0 && r < N_NODES) acc += skern[k] * npred[r * 5 + ch];
                }
                sc[ch] = acc;
            }
            float m = sc[0];
            #pragma unroll
            for (int ch = 1; ch < 5; ++ch) m = fmaxf(m, sc[ch]);
            float sum = 0.f;
            #pragma unroll
            for (int ch = 0; ch < 5; ++ch) sum += __expf(sc[ch] - m);
            abn_lds[node] = __expf(sc[0] - m) / sum;
        }
        __syncthreads();
        if (tid < 64) {
            int lane = tid;
            int count = 0;
            for (int c = 0; c < N_NODES / 64; ++c) {
                int node = c * 64 + lane;
                float tp = tpin[node] * al;
                bool in = (tp >= s0) && (tp <= e0);
                unsigned long long m = __ballot(in);
                if (in) {
                    int pos = count + __popcll(m & ((1ull << lane) - 1ull));
                    members[a * N_NODES + pos] = node;
                    memloc[pos] = node;
                }
                count += __popcll(m);
            }
            if (lane == 0) lens[a] = count;
            int sc3 = a >> 6;
            float h = 0.f;
            if (lane < 2) {
                int sd = sc3 * 2 + lane;
                float wi0 = aWih[sd*3+0], wi1 = aWih[sd*3+1], wi2 = aWih[sd*3+2];
                float wh0 = aWhh[sd*3+0], wh1 = aWhh[sd*3+1], wh2 = aWhh[sd*3+2];
                float bi0 = abih[sd*3+0], bi1 = abih[sd*3+1], bi2 = abih[sd*3+2];
                float bh0 = abhh[sd*3+0], bh1 = abhh[sd*3+1], bh2 = abhh[sd*3+2];
                for (int t = 0; t < count; ++t) {
                    int idx = lane ? (count - 1 - t) : t;
                    float xv = abn_lds[memloc[idx]];
                    float r = fast_sigmoid(fmaf(wi0, xv, bi0) + fmaf(wh0, h, bh0));
                    float z = fast_sigmoid(fmaf(wi1, xv, bi1) + fmaf(wh1, h, bh1));
                    float nv = fast_tanh(fmaf(wi2, xv, bi2) + r * fmaf(wh2, h, bh2));
                    h = (1.f - z) * nv + z * h;
                }
            }
            float hb = __shfl(h, 1);
            if (lane == 0) abn_res[a] = 0.5f * (h + hb);
        }
    }
}

// ============ Kernel 2: H=128 GRU (EXACT R8 body) + block-pair-fused MLP head ============
// grid: 384 blocks = (anchor, dir) — the R8 optimum: VGPR-64 live set (hj re-read from
// LDS!), 2-block/CU TLP hides the weight-remat chain. After feat is written, blocks
// (a,0)/(a,1) handshake via device-scope atomicAdd; the SECOND finisher runs anchor a's
// head inline — eliminating the 3rd dispatch (~30 us/dispatch boundary, R4-vs-R8 data).
__global__ __launch_bounds__(512, 2) void gru_feat_kernel(
    const float* __restrict__ xW, const float* __restrict__ Whh,
    const float* __restrict__ bhh, const int* __restrict__ members,
    const int* __restrict__ lens, float* __restrict__ feat_out,
    int* __restrict__ flags, const float* __restrict__ abn_res,
    const float* __restrict__ anchors, const float* __restrict__ alp,
    const float* __restrict__ W1, const float* __restrict__ b1,
    const float* __restrict__ W2, const float* __restrict__ b2,
    const float* __restrict__ W3, const float* __restrict__ b3,
    const float* __restrict__ sw, const float* __restrict__ ew,
    float* __restrict__ out)
{
    int b = blockIdx.x;
    int a = b >> 1;
    int dir = b & 1;
    int s3 = a >> 6;           // scale
    int sd = s3 * 2 + dir;
    int t0 = threadIdx.x;      // 0..511
    int j  = t0 >> 2;          // 0..127 : owned h element
    int s  = t0 & 3;           // 0..3   : 32-wide K slice

    // preload this thread's Whh slices (compiler remats these loads; that's the measured optimum)
    float wr[32], wz[32], wn[32];
    {
        const float* base = Whh + ((size_t)sd * G3) * DIM;
        const float* pr = base + (size_t)(j        ) * DIM + s * 32;
        const float* pz = base + (size_t)(j + DIM  ) * DIM + s * 32;
        const float* pn = base + (size_t)(j + 2*DIM) * DIM + s * 32;
        #pragma unroll
        for (int q = 0; q < 8; ++q) {
            float4 v = *(const float4*)(pr + 4 * q);
            wr[4*q+0]=v.x; wr[4*q+1]=v.y; wr[4*q+2]=v.z; wr[4*q+3]=v.w;
        }
        #pragma unroll
        for (int q = 0; q < 8; ++q) {
            float4 v = *(const float4*)(pz + 4 * q);
            wz[4*q+0]=v.x; wz[4*q+1]=v.y; wz[4*q+2]=v.z; wz[4*q+3]=v.w;
        }
        #pragma unroll
        for (int q = 0; q < 8; ++q) {
            float4 v = *(const float4*)(pn + 4 * q);
            wn[4*q+0]=v.x; wn[4*q+1]=v.y; wn[4*q+2]=v.z; wn[4*q+3]=v.w;
        }
    }
    float bhr = bhh[sd * G3 + j];
    float bhz = bhh[sd * G3 + DIM + j];
    float bhn = bhh[sd * G3 + 2 * DIM + j];

    const float* xWp = xW + (size_t)sd * N_NODES * G3;
    const int* mem = members + a * N_NODES;
    int len = lens[a];

    // h ping-pong, slice-padded: slice s at [buf][s][0..31], stride 36 floats
    __shared__ __align__(16) float hbuf[2][4][36];
    for (int i = t0; i < 2 * 4 * 36; i += 512) ((float*)hbuf)[i] = 0.f;
    __syncthreads();

    // prefetch gi for step 0
    int node0 = (len > 0) ? mem[dir ? (len - 1) : 0] : 0;
    float gr = xWp[(size_t)node0 * G3 + j];
    float gz = xWp[(size_t)node0 * G3 + DIM + j];
    float gn = xWp[(size_t)node0 * G3 + 2 * DIM + j];

    int cur = 0;
    for (int t = 0; t < len; ++t) {
        // prefetch next step's gi (overlaps this step's compute + barrier)
        float gr_n = 0.f, gz_n = 0.f, gn_n = 0.f;
        if (t + 1 < len) {
            int nn = mem[dir ? (len - 2 - t) : (t + 1)];
            gr_n = xWp[(size_t)nn * G3 + j];
            gz_n = xWp[(size_t)nn * G3 + DIM + j];
            gn_n = xWp[(size_t)nn * G3 + 2 * DIM + j];
        }
        // partial dots over this thread's 32-wide K slice
        float ar = 0.f, az = 0.f, an_ = 0.f;
        const float4* hp = (const float4*)(&hbuf[cur][s][0]);
        #pragma unroll
        for (int q = 0; q < 8; ++q) {
            float4 hv = hp[q];
            ar = fmaf(wr[4*q+0], hv.x, ar); ar = fmaf(wr[4*q+1], hv.y, ar);
            ar = fmaf(wr[4*q+2], hv.z, ar); ar = fmaf(wr[4*q+3], hv.w, ar);
            az = fmaf(wz[4*q+0], hv.x, az); az = fmaf(wz[4*q+1], hv.y, az);
            az = fmaf(wz[4*q+2], hv.z, az); az = fmaf(wz[4*q+3], hv.w, az);
            an_ = fmaf(wn[4*q+0], hv.x, an_); an_ = fmaf(wn[4*q+1], hv.y, an_);
            an_ = fmaf(wn[4*q+2], hv.z, an_); an_ = fmaf(wn[4*q+3], hv.w, an_);
        }
        // quad reduction (lanes 4j..4j+3 adjacent in wave)
        ar  += __shfl_xor(ar, 1);  ar  += __shfl_xor(ar, 2);
        az  += __shfl_xor(az, 1);  az  += __shfl_xor(az, 2);
        an_ += __shfl_xor(an_, 1); an_ += __shfl_xor(an_, 2);

        float r  = fast_sigmoid(gr + ar + bhr);
        float z  = fast_sigmoid(gz + az + bhz);
        float nv = fast_tanh(gn + r * (an_ + bhn));
        float hj = hbuf[cur][j >> 5][j & 31];     // LDS re-read: keeps live set at 64 VGPR
        float hnew = (1.f - z) * nv + z * hj;
        if (s == 0) hbuf[cur ^ 1][j >> 5][j & 31] = hnew;
        __syncthreads();
        cur ^= 1;
        gr = gr_n; gz = gz_n; gn = gn_n;
    }
    if (s == 0) feat_out[a * 256 + dir * DIM + j] = hbuf[cur][j >> 5][j & 31];

    // ---------------- block-pair handshake: 2nd finisher runs the head ----------------
    __syncthreads();                 // all feat stores issued by this block
    __shared__ int winner;
    if (t0 == 0) {
        __threadfence();             // release: feat visible device-wide before flag bump
        winner = atomicAdd(&flags[a], 1);
    }
    __syncthreads();                 // winner is block-uniform
    if (winner != 1) return;
    __threadfence();                 // acquire: other block's feat stores visible

    __shared__ float sf[260];
    __shared__ float h1[256];
    __shared__ float h2[256];
    __shared__ float o[FOUT];
    float al = alp[0];
    float st = anchors[a * 2 + 0];
    float en = anchors[a * 2 + 1];
    if (t0 < 256) sf[t0] = feat_out[a * 256 + t0];
    if (t0 == 0) {
        sf[256] = abn_res[a];
        sf[257] = (st + en) * 0.5f / al;
        sf[258] = (en - st) / al;
    }
    __syncthreads();

    if (t0 < 256) {
        const float* w1 = W1 + (size_t)s3 * 259 * 256;
        float acc = b1[s3 * 256 + t0];
        for (int jj = 0; jj < 259; ++jj) acc = fmaf(sf[jj], w1[jj * 256 + t0], acc);
        h1[t0] = fmaxf(acc, 0.f);
    }
    __syncthreads();
    if (t0 < 256) {
        const float* w2 = W2 + (size_t)s3 * 256 * 256;
        float acc = b2[s3 * 256 + t0];
        for (int jj = 0; jj < 256; ++jj) acc = fmaf(h1[jj], w2[jj * 256 + t0], acc);
        h2[t0] = fmaxf(acc, 0.f);
    }
    __syncthreads();
    if (t0 < FOUT) {
        const float* w3 = W3 + (size_t)s3 * 256 * FOUT;
        float acc = b3[s3 * FOUT + t0];
        for (int jj = 0; jj < 256; ++jj) acc = fmaf(h2[jj], w3[jj * FOUT + t0], acc);
        o[t0] = acc;
    }
    __syncthreads();
    if (t0 < 2) {   // t0 0: start offset, t0 1: end offset
        const float* lw = (t0 == 0) ? (sw + s3 * DBINS) : (ew + s3 * DBINS);
        const float* sl = o + t0 * DBINS;
        float m = sl[0];
        for (int jj = 1; jj < DBINS; ++jj) m = fmaxf(m, sl[jj]);
        float sum = 0.f, dot = 0.f;
        for (int jj = 0; jj < DBINS; ++jj) {
            float e = __expf(sl[jj] - m);
            sum += e;
            dot = fmaf(e, lw[jj], dot);
        }
        float off = dot / sum;
        float base = (t0 == 0) ? st : en;
        out[a * 2 + t0] = fminf(fmaxf(base + off, 0.f), al);
    }
    if (t0 == 42) out[2 * NANCH + a] = o[42];                             // conf
    if (t0 >= 43 && t0 < FOUT) out[3 * NANCH + a * 4 + (t0 - 43)] = o[t0]; // cls
}

extern "C" void kernel_launch(void* const* d_in, const int* in_sizes, int n_in,
                              void* d_out, int out_size, void* d_ws, size_t ws_size,
                              hipStream_t stream) {
    const float* emb   = (const float*)d_in[0];
    const float* tpin  = (const float*)d_in[1];
    const float* npred = (const float*)d_in[2];
    const float* alp   = (const float*)d_in[3];
    const float* anch  = (const float*)d_in[4];
    const float* skern = (const float*)d_in[5];
    const float* fWih  = (const float*)d_in[6];
    const float* fWhh  = (const float*)d_in[7];
    const float* fbih  = (const float*)d_in[8];
    const float* fbhh  = (const float*)d_in[9];
    const float* aWih  = (const float*)d_in[10];
    const float* aWhh  = (const float*)d_in[11];
    const float* abih  = (const float*)d_in[12];
    const float* abhh  = (const float*)d_in[13];
    const float* sw    = (const float*)d_in[14];
    const float* ew    = (const float*)d_in[15];
    const float* W1    = (const float*)d_in[16];
    const float* b1    = (const float*)d_in[17];
    const float* W2    = (const float*)d_in[18];
    const float* b2    = (const float*)d_in[19];
    const float* W3    = (const float*)d_in[20];
    const float* b3    = (const float*)d_in[21];

    float* ws = (float*)d_ws;
    float* xW       = ws;                      // 6*512*384 = 1179648
    float* abn_res  = ws + 1179648;            // 192 (pad 256)
    float* feat     = ws + 1179904;            // 192*256 = 49152
    int*   members  = (int*)(ws + 1229056);    // 192*512 ints = 98304
    int*   lens     = (int*)(ws + 1327360);    // 192 ints (pad 256)
    int*   flags    = (int*)(ws + 1327616);    // 192 ints
    float* outp     = (float*)d_out;

    prep_kernel<<<384, 384, 0, stream>>>(emb, tpin, fWih, fbih, alp, anch, npred, skern,
                                         aWih, aWhh, abih, abhh,
                                         xW, members, lens, abn_res, flags);
    gru_feat_kernel<<<2 * NANCH, 512, 0, stream>>>(xW, fWhh, fbhh, members, lens, feat,
                                                   flags, abn_res, anch, alp,
                                                   W1, b1, W2, b2, W3, b3, sw, ew, outp);
}

// Round 11
// 251.078 us; speedup vs baseline: 1.1299x; 1.0631x over previous
//
#include <hip/hip_runtime.h>
#include <math.h>

#define N_NODES 512
#define DIM 128
#define NANCH 192
#define G3 384           // 3*DIM gate width
#define FOUT 47
#define DBINS 21

__device__ __forceinline__ float fast_sigmoid(float x) {
    return __builtin_amdgcn_rcpf(1.f + __expf(-x));
}
__device__ __forceinline__ float fast_tanh(float x) {
    return 1.f - 2.f * __builtin_amdgcn_rcpf(1.f + __expf(2.f * x));
}

// ============ Kernel 1: fused [xW GEMM | membership + abnormal + H=1 BiGRU] ============
// blocks 0..191   : xW = x @ Wih^T + bih  (sd = blk>>5, node-group = blk&31)
// blocks 192..383 : per-anchor membership list + abnormal scores + scalar BiGRU
__global__ __launch_bounds__(384) void prep_kernel(
    const float* __restrict__ emb, const float* __restrict__ tpin,
    const float* __restrict__ Wih, const float* __restrict__ bih,
    const float* __restrict__ alp, const float* __restrict__ anchors,
    const float* __restrict__ npred, const float* __restrict__ skern,
    const float* __restrict__ aWih, const float* __restrict__ aWhh,
    const float* __restrict__ abih, const float* __restrict__ abhh,
    float* __restrict__ xW, int* __restrict__ members,
    int* __restrict__ lens, float* __restrict__ abn_res)
{
    int blk = blockIdx.x;
    int tid = threadIdx.x;     // 0..383
    if (blk < 192) {
        int sd = blk >> 5;         // 0..5
        int ng = blk & 31;         // 0..31
        __shared__ __align__(16) float xs[16][DIM];
        for (int idx = tid; idx < 16 * DIM; idx += 384) {
            int m = idx >> 7, k = idx & 127;
            int node = ng * 16 + m;
            float tv = tpin[node];
            float freq = 10.f * (float)k / 127.f;
            xs[m][k] = emb[node * DIM + k] + 0.05f * __sinf(tv * freq);
        }
        __syncthreads();
        float acc[16];
        float b = bih[sd * G3 + tid];
        #pragma unroll
        for (int m = 0; m < 16; ++m) acc[m] = b;
        const float* wrow = Wih + ((size_t)sd * G3 + tid) * DIM;
        for (int k = 0; k < DIM; k += 4) {
            float4 w4 = *(const float4*)(wrow + k);
            #pragma unroll
            for (int m = 0; m < 16; ++m) {
                float4 xv = *(const float4*)&xs[m][k];   // wave-uniform b128 broadcast
                acc[m] = fmaf(w4.x, xv.x, acc[m]);
                acc[m] = fmaf(w4.y, xv.y, acc[m]);
                acc[m] = fmaf(w4.z, xv.z, acc[m]);
                acc[m] = fmaf(w4.w, xv.w, acc[m]);
            }
        }
        #pragma unroll
        for (int m = 0; m < 16; ++m)
            xW[((size_t)sd * N_NODES + ng * 16 + m) * G3 + tid] = acc[m];
    } else {
        int a = blk - 192;
        float al = alp[0];
        float s0 = anchors[a * 2 + 0];
        float e0 = anchors[a * 2 + 1];
        __shared__ int memloc[N_NODES];
        __shared__ float abn_lds[N_NODES];
        for (int node = tid; node < N_NODES; node += 384) {
            float sc[5];
            #pragma unroll
            for (int ch = 0; ch < 5; ++ch) {
                float acc = 0.f;
                #pragma unroll
                for (int k = 0; k < 5; ++k) {
                    int r = node + k - 2;
                    if (r >= 0 && r < N_NODES) acc += skern[k] * npred[r * 5 + ch];
                }
                sc[ch] = acc;
            }
            float m = sc[0];
            #pragma unroll
            for (int ch = 1; ch < 5; ++ch) m = fmaxf(m, sc[ch]);
            float sum = 0.f;
            #pragma unroll
            for (int ch = 0; ch < 5; ++ch) sum += __expf(sc[ch] - m);
            abn_lds[node] = __expf(sc[0] - m) / sum;
        }
        __syncthreads();
        if (tid < 64) {
            int lane = tid;
            int count = 0;
            for (int c = 0; c < N_NODES / 64; ++c) {
                int node = c * 64 + lane;
                float tp = tpin[node] * al;
                bool in = (tp >= s0) && (tp <= e0);
                unsigned long long m = __ballot(in);
                if (in) {
                    int pos = count + __popcll(m & ((1ull << lane) - 1ull));
                    members[a * N_NODES + pos] = node;
                    memloc[pos] = node;
                }
                count += __popcll(m);
            }
            if (lane == 0) lens[a] = count;
            int sc3 = a >> 6;
            float h = 0.f;
            if (lane < 2) {
                int sd = sc3 * 2 + lane;
                float wi0 = aWih[sd*3+0], wi1 = aWih[sd*3+1], wi2 = aWih[sd*3+2];
                float wh0 = aWhh[sd*3+0], wh1 = aWhh[sd*3+1], wh2 = aWhh[sd*3+2];
                float bi0 = abih[sd*3+0], bi1 = abih[sd*3+1], bi2 = abih[sd*3+2];
                float bh0 = abhh[sd*3+0], bh1 = abhh[sd*3+1], bh2 = abhh[sd*3+2];
                for (int t = 0; t < count; ++t) {
                    int idx = lane ? (count - 1 - t) : t;
                    float xv = abn_lds[memloc[idx]];
                    float r = fast_sigmoid(fmaf(wi0, xv, bi0) + fmaf(wh0, h, bh0));
                    float z = fast_sigmoid(fmaf(wi1, xv, bi1) + fmaf(wh1, h, bh1));
                    float nv = fast_tanh(fmaf(wi2, xv, bi2) + r * fmaf(wh2, h, bh2));
                    h = (1.f - z) * nv + z * h;
                }
            }
            float hb = __shfl(h, 1);
            if (lane == 0) abn_res[a] = 0.5f * (h + hb);
        }
    }
}

// ============ Kernel 2: H=128 GRU recurrence — EXACT R2/R8 body (105.8 us, VGPR 64) ============
// grid: 384 blocks = (anchor, dir). 512 threads: thread = (j = t>>2, s = t&3).
// CRITICAL invariants (each violation measured as a regression):
//  - hj RE-READ from LDS each step -> live set exactly 64 VGPR (65+ halves wave capacity; R7).
//  - no pins / no waves_per_eu / no appended phases (R3/R5/R6/R10 all regressed).
//  - 384 blocks @ 2 blocks/CU: cross-block TLP is what hides the per-step L1/L2
//    weight-remat stream (~384 KB/step/CU); 192-block variants lose it (R9).
__global__ __launch_bounds__(512, 2) void gru_feat_kernel(
    const float* __restrict__ xW, const float* __restrict__ Whh,
    const float* __restrict__ bhh, const int* __restrict__ members,
    const int* __restrict__ lens, float* __restrict__ feat_out)
{
    int b = blockIdx.x;
    int a = b >> 1;
    int dir = b & 1;
    int s3 = a >> 6;           // scale
    int sd = s3 * 2 + dir;
    int t0 = threadIdx.x;      // 0..511
    int j  = t0 >> 2;          // 0..127 : owned h element
    int s  = t0 & 3;           // 0..3   : 32-wide K slice

    // preload this thread's Whh slices (compiler remats these loads; that's the measured optimum)
    float wr[32], wz[32], wn[32];
    {
        const float* base = Whh + ((size_t)sd * G3) * DIM;
        const float* pr = base + (size_t)(j        ) * DIM + s * 32;
        const float* pz = base + (size_t)(j + DIM  ) * DIM + s * 32;
        const float* pn = base + (size_t)(j + 2*DIM) * DIM + s * 32;
        #pragma unroll
        for (int q = 0; q < 8; ++q) {
            float4 v = *(const float4*)(pr + 4 * q);
            wr[4*q+0]=v.x; wr[4*q+1]=v.y; wr[4*q+2]=v.z; wr[4*q+3]=v.w;
        }
        #pragma unroll
        for (int q = 0; q < 8; ++q) {
            float4 v = *(const float4*)(pz + 4 * q);
            wz[4*q+0]=v.x; wz[4*q+1]=v.y; wz[4*q+2]=v.z; wz[4*q+3]=v.w;
        }
        #pragma unroll
        for (int q = 0; q < 8; ++q) {
            float4 v = *(const float4*)(pn + 4 * q);
            wn[4*q+0]=v.x; wn[4*q+1]=v.y; wn[4*q+2]=v.z; wn[4*q+3]=v.w;
        }
    }
    float bhr = bhh[sd * G3 + j];
    float bhz = bhh[sd * G3 + DIM + j];
    float bhn = bhh[sd * G3 + 2 * DIM + j];

    const float* xWp = xW + (size_t)sd * N_NODES * G3;
    const int* mem = members + a * N_NODES;
    int len = lens[a];

    // h ping-pong, slice-padded: slice s at [buf][s][0..31], stride 36 floats
    __shared__ __align__(16) float hbuf[2][4][36];
    for (int i = t0; i < 2 * 4 * 36; i += 512) ((float*)hbuf)[i] = 0.f;
    __syncthreads();

    // prefetch gi for step 0
    int node0 = (len > 0) ? mem[dir ? (len - 1) : 0] : 0;
    float gr = xWp[(size_t)node0 * G3 + j];
    float gz = xWp[(size_t)node0 * G3 + DIM + j];
    float gn = xWp[(size_t)node0 * G3 + 2 * DIM + j];

    int cur = 0;
    for (int t = 0; t < len; ++t) {
        // prefetch next step's gi (overlaps this step's compute + barrier)
        float gr_n = 0.f, gz_n = 0.f, gn_n = 0.f;
        if (t + 1 < len) {
            int nn = mem[dir ? (len - 2 - t) : (t + 1)];
            gr_n = xWp[(size_t)nn * G3 + j];
            gz_n = xWp[(size_t)nn * G3 + DIM + j];
            gn_n = xWp[(size_t)nn * G3 + 2 * DIM + j];
        }
        // partial dots over this thread's 32-wide K slice
        float ar = 0.f, az = 0.f, an_ = 0.f;
        const float4* hp = (const float4*)(&hbuf[cur][s][0]);
        #pragma unroll
        for (int q = 0; q < 8; ++q) {
            float4 hv = hp[q];
            ar = fmaf(wr[4*q+0], hv.x, ar); ar = fmaf(wr[4*q+1], hv.y, ar);
            ar = fmaf(wr[4*q+2], hv.z, ar); ar = fmaf(wr[4*q+3], hv.w, ar);
            az = fmaf(wz[4*q+0], hv.x, az); az = fmaf(wz[4*q+1], hv.y, az);
            az = fmaf(wz[4*q+2], hv.z, az); az = fmaf(wz[4*q+3], hv.w, az);
            an_ = fmaf(wn[4*q+0], hv.x, an_); an_ = fmaf(wn[4*q+1], hv.y, an_);
            an_ = fmaf(wn[4*q+2], hv.z, an_); an_ = fmaf(wn[4*q+3], hv.w, an_);
        }
        // quad reduction (lanes 4j..4j+3 adjacent in wave)
        ar  += __shfl_xor(ar, 1);  ar  += __shfl_xor(ar, 2);
        az  += __shfl_xor(az, 1);  az  += __shfl_xor(az, 2);
        an_ += __shfl_xor(an_, 1); an_ += __shfl_xor(an_, 2);

        float r  = fast_sigmoid(gr + ar + bhr);
        float z  = fast_sigmoid(gz + az + bhz);
        float nv = fast_tanh(gn + r * (an_ + bhn));
        float hj = hbuf[cur][j >> 5][j & 31];     // LDS re-read: keeps live set at 64 VGPR
        float hnew = (1.f - z) * nv + z * hj;
        if (s == 0) hbuf[cur ^ 1][j >> 5][j & 31] = hnew;
        __syncthreads();
        cur ^= 1;
        gr = gr_n; gz = gz_n; gn = gn_n;
    }
    if (s == 0) feat_out[a * 256 + dir * DIM + j] = hbuf[cur][j >> 5][j & 31];
}

// ============ Kernel 3: per-anchor MLP head + boundary refinement ============
__global__ __launch_bounds__(256) void head_kernel(
    const float* __restrict__ feat, const float* __restrict__ abn_res,
    const float* __restrict__ anchors, const float* __restrict__ alp,
    const float* __restrict__ W1, const float* __restrict__ b1,
    const float* __restrict__ W2, const float* __restrict__ b2,
    const float* __restrict__ W3, const float* __restrict__ b3,
    const float* __restrict__ sw, const float* __restrict__ ew,
    float* __restrict__ out)
{
    int a = blockIdx.x;
    int tid = threadIdx.x;   // 0..255
    int s = a >> 6;
    __shared__ float sf[260];
    __shared__ float h1[256];
    __shared__ float h2[256];
    __shared__ float o[FOUT];
    float al = alp[0];
    float st = anchors[a * 2 + 0];
    float en = anchors[a * 2 + 1];
    sf[tid] = feat[a * 256 + tid];
    if (tid == 0) {
        sf[256] = abn_res[a];
        sf[257] = (st + en) * 0.5f / al;
        sf[258] = (en - st) / al;
    }
    __syncthreads();

    const float* w1 = W1 + (size_t)s * 259 * 256;
    float acc = b1[s * 256 + tid];
    for (int jj = 0; jj < 259; ++jj) acc = fmaf(sf[jj], w1[jj * 256 + tid], acc);
    h1[tid] = fmaxf(acc, 0.f);
    __syncthreads();

    const float* w2 = W2 + (size_t)s * 256 * 256;
    acc = b2[s * 256 + tid];
    for (int jj = 0; jj < 256; ++jj) acc = fmaf(h1[jj], w2[jj * 256 + tid], acc);
    h2[tid] = fmaxf(acc, 0.f);
    __syncthreads();

    if (tid < FOUT) {
        const float* w3 = W3 + (size_t)s * 256 * FOUT;
        acc = b3[s * FOUT + tid];
        for (int jj = 0; jj < 256; ++jj) acc = fmaf(h2[jj], w3[jj * FOUT + tid], acc);
        o[tid] = acc;
    }
    __syncthreads();

    if (tid < 2) {   // tid 0: start offset, tid 1: end offset
        const float* lw = (tid == 0) ? (sw + s * DBINS) : (ew + s * DBINS);
        const float* sl = o + tid * DBINS;
        float m = sl[0];
        for (int jj = 1; jj < DBINS; ++jj) m = fmaxf(m, sl[jj]);
        float sum = 0.f, dot = 0.f;
        for (int jj = 0; jj < DBINS; ++jj) {
            float e = __expf(sl[jj] - m);
            sum += e;
            dot = fmaf(e, lw[jj], dot);
        }
        float off = dot / sum;
        float base = (tid == 0) ? st : en;
        out[a * 2 + tid] = fminf(fmaxf(base + off, 0.f), al);
    }
    if (tid == 42) out[2 * NANCH + a] = o[42];                           // conf
    if (tid >= 43 && tid < FOUT) out[3 * NANCH + a * 4 + (tid - 43)] = o[tid]; // cls
}

extern "C" void kernel_launch(void* const* d_in, const int* in_sizes, int n_in,
                              void* d_out, int out_size, void* d_ws, size_t ws_size,
                              hipStream_t stream) {
    const float* emb   = (const float*)d_in[0];
    const float* tpin  = (const float*)d_in[1];
    const float* npred = (const float*)d_in[2];
    const float* alp   = (const float*)d_in[3];
    const float* anch  = (const float*)d_in[4];
    const float* skern = (const float*)d_in[5];
    const float* fWih  = (const float*)d_in[6];
    const float* fWhh  = (const float*)d_in[7];
    const float* fbih  = (const float*)d_in[8];
    const float* fbhh  = (const float*)d_in[9];
    const float* aWih  = (const float*)d_in[10];
    const float* aWhh  = (const float*)d_in[11];
    const float* abih  = (const float*)d_in[12];
    const float* abhh  = (const float*)d_in[13];
    const float* sw    = (const float*)d_in[14];
    const float* ew    = (const float*)d_in[15];
    const float* W1    = (const float*)d_in[16];
    const float* b1    = (const float*)d_in[17];
    const float* W2    = (const float*)d_in[18];
    const float* b2    = (const float*)d_in[19];
    const float* W3    = (const float*)d_in[20];
    const float* b3    = (const float*)d_in[21];

    float* ws = (float*)d_ws;
    float* xW       = ws;                      // 6*512*384 = 1179648
    float* abn_res  = ws + 1179648;            // 192 (pad 256)
    float* feat     = ws + 1179904;            // 192*256 = 49152
    int*   members  = (int*)(ws + 1229056);    // 192*512 ints = 98304
    int*   lens     = (int*)(ws + 1327360);    // 192 ints
    float* outp     = (float*)d_out;

    prep_kernel<<<384, 384, 0, stream>>>(emb, tpin, fWih, fbih, alp, anch, npred, skern,
                                         aWih, aWhh, abih, abhh,
                                         xW, members, lens, abn_res);
    gru_feat_kernel<<<2 * NANCH, 512, 0, stream>>>(xW, fWhh, fbhh, members, lens, feat);
    head_kernel<<<NANCH, 256, 0, stream>>>(feat, abn_res, anch, alp,
                                           W1, b1, W2, b2, W3, b3, sw, ew, outp);
}

// Round 12
// 235.502 us; speedup vs baseline: 1.2046x; 1.0661x over previous
//
#include <hip/hip_runtime.h>
#include <math.h>

#define N_NODES 512
#define DIM 128
#define NANCH 192
#define G3 384           // 3*DIM gate width
#define FOUT 47
#define DBINS 21

__device__ __forceinline__ float fast_sigmoid(float x) {
    return __builtin_amdgcn_rcpf(1.f + __expf(-x));
}
__device__ __forceinline__ float fast_tanh(float x) {
    return 1.f - 2.f * __builtin_amdgcn_rcpf(1.f + __expf(2.f * x));
}

// ============ Kernel 1: fused [xW GEMM | membership + abnormal + H=1 BiGRU] ============
// blocks 0..191   : xW = x @ Wih^T + bih  (sd = blk>>5, node-group = blk&31)
// blocks 192..383 : per-anchor membership list + abnormal scores + scalar BiGRU
__global__ __launch_bounds__(384) void prep_kernel(
    const float* __restrict__ emb, const float* __restrict__ tpin,
    const float* __restrict__ Wih, const float* __restrict__ bih,
    const float* __restrict__ alp, const float* __restrict__ anchors,
    const float* __restrict__ npred, const float* __restrict__ skern,
    const float* __restrict__ aWih, const float* __restrict__ aWhh,
    const float* __restrict__ abih, const float* __restrict__ abhh,
    float* __restrict__ xW, int* __restrict__ members,
    int* __restrict__ lens, float* __restrict__ abn_res)
{
    int blk = blockIdx.x;
    int tid = threadIdx.x;     // 0..383
    if (blk < 192) {
        int sd = blk >> 5;         // 0..5
        int ng = blk & 31;         // 0..31
        __shared__ __align__(16) float xs[16][DIM];
        for (int idx = tid; idx < 16 * DIM; idx += 384) {
            int m = idx >> 7, k = idx & 127;
            int node = ng * 16 + m;
            float tv = tpin[node];
            float freq = 10.f * (float)k / 127.f;
            xs[m][k] = emb[node * DIM + k] + 0.05f * __sinf(tv * freq);
        }
        __syncthreads();
        float acc[16];
        float b = bih[sd * G3 + tid];
        #pragma unroll
        for (int m = 0; m < 16; ++m) acc[m] = b;
        const float* wrow = Wih + ((size_t)sd * G3 + tid) * DIM;
        for (int k = 0; k < DIM; k += 4) {
            float4 w4 = *(const float4*)(wrow + k);
            #pragma unroll
            for (int m = 0; m < 16; ++m) {
                float4 xv = *(const float4*)&xs[m][k];   // wave-uniform b128 broadcast
                acc[m] = fmaf(w4.x, xv.x, acc[m]);
                acc[m] = fmaf(w4.y, xv.y, acc[m]);
                acc[m] = fmaf(w4.z, xv.z, acc[m]);
                acc[m] = fmaf(w4.w, xv.w, acc[m]);
            }
        }
        #pragma unroll
        for (int m = 0; m < 16; ++m)
            xW[((size_t)sd * N_NODES + ng * 16 + m) * G3 + tid] = acc[m];
    } else {
        int a = blk - 192;
        float al = alp[0];
        float s0 = anchors[a * 2 + 0];
        float e0 = anchors[a * 2 + 1];
        __shared__ int memloc[N_NODES];
        __shared__ float abn_lds[N_NODES];
        for (int node = tid; node < N_NODES; node += 384) {
            float sc[5];
            #pragma unroll
            for (int ch = 0; ch < 5; ++ch) {
                float acc = 0.f;
                #pragma unroll
                for (int k = 0; k < 5; ++k) {
                    int r = node + k - 2;
                    if (r >= 0 && r < N_NODES) acc += skern[k] * npred[r * 5 + ch];
                }
                sc[ch] = acc;
            }
            float m = sc[0];
            #pragma unroll
            for (int ch = 1; ch < 5; ++ch) m = fmaxf(m, sc[ch]);
            float sum = 0.f;
            #pragma unroll
            for (int ch = 0; ch < 5; ++ch) sum += __expf(sc[ch] - m);
            abn_lds[node] = __expf(sc[0] - m) / sum;
        }
        __syncthreads();
        if (tid < 64) {
            int lane = tid;
            int count = 0;
            for (int c = 0; c < N_NODES / 64; ++c) {
                int node = c * 64 + lane;
                float tp = tpin[node] * al;
                bool in = (tp >= s0) && (tp <= e0);
                unsigned long long m = __ballot(in);
                if (in) {
                    int pos = count + __popcll(m & ((1ull << lane) - 1ull));
                    members[a * N_NODES + pos] = node;
                    memloc[pos] = node;
                }
                count += __popcll(m);
            }
            if (lane == 0) lens[a] = count;
            int sc3 = a >> 6;
            float h = 0.f;
            if (lane < 2) {
                int sd = sc3 * 2 + lane;
                float wi0 = aWih[sd*3+0], wi1 = aWih[sd*3+1], wi2 = aWih[sd*3+2];
                float wh0 = aWhh[sd*3+0], wh1 = aWhh[sd*3+1], wh2 = aWhh[sd*3+2];
                float bi0 = abih[sd*3+0], bi1 = abih[sd*3+1], bi2 = abih[sd*3+2];
                float bh0 = abhh[sd*3+0], bh1 = abhh[sd*3+1], bh2 = abhh[sd*3+2];
                for (int t = 0; t < count; ++t) {
                    int idx = lane ? (count - 1 - t) : t;
                    float xv = abn_lds[memloc[idx]];
                    float r = fast_sigmoid(fmaf(wi0, xv, bi0) + fmaf(wh0, h, bh0));
                    float z = fast_sigmoid(fmaf(wi1, xv, bi1) + fmaf(wh1, h, bh1));
                    float nv = fast_tanh(fmaf(wi2, xv, bi2) + r * fmaf(wh2, h, bh2));
                    h = (1.f - z) * nv + z * h;
                }
            }
            float hb = __shfl(h, 1);
            if (lane == 0) abn_res[a] = 0.5f * (h + hb);
        }
    }
}

// ============ Kernel 2: H=128 GRU recurrence — R8 body + sorted block placement ============
// Inner loop byte-identical to R8 (105.8 us, VGPR 64). ONLY change: anchor->block
// assignment. HW maps blocks (b, b+256) to the same CU (round-robin over 8 XCDs x 32
// CUs), so blocks 128..255 run SOLO while 0..127 / 256..383 share a CU. Anchors are
// ranked by interval width (len proxy, from anchors[] directly — no extra sync) and
// the 64 longest anchors get the solo block IDs: the makespan straggler runs at the
// solo per-step rate instead of the shared rate.
__global__ __launch_bounds__(512, 2) void gru_feat_kernel(
    const float* __restrict__ xW, const float* __restrict__ Whh,
    const float* __restrict__ bhh, const int* __restrict__ members,
    const int* __restrict__ lens, const float* __restrict__ anchors,
    float* __restrict__ feat_out)
{
    int b = blockIdx.x;
    int t0 = threadIdx.x;      // 0..511
    int j  = t0 >> 2;          // 0..127 : owned h element
    int s  = t0 & 3;           // 0..3   : 32-wide K slice

    // ---- rank anchors by width desc (bijective; ties broken by index) ----
    __shared__ int perm_l[NANCH];
    if (t0 < NANCH) {
        float w = anchors[2 * t0 + 1] - anchors[2 * t0];
        int rank = 0;
        for (int q = 0; q < NANCH; ++q) {
            float wq = anchors[2 * q + 1] - anchors[2 * q];
            rank += (wq > w) || (wq == w && q < t0);
        }
        perm_l[rank] = t0;
    }
    __syncthreads();
    int k, dir;
    if (b >= 128 && b < 256) { int i = b - 128; k = i >> 1;        dir = i & 1; } // ranks 0..63  (solo CUs)
    else if (b < 128)        {                  k = 64 + (b >> 1); dir = b & 1; } // ranks 64..127 (shared)
    else                     { int i = b - 256; k = 128 + (i >> 1); dir = i & 1; } // ranks 128..191 (shared)
    int a  = perm_l[k];
    int s3 = a >> 6;           // scale
    int sd = s3 * 2 + dir;

    // preload this thread's Whh slices (compiler remats these loads; that's the measured optimum)
    float wr[32], wz[32], wn[32];
    {
        const float* base = Whh + ((size_t)sd * G3) * DIM;
        const float* pr = base + (size_t)(j        ) * DIM + s * 32;
        const float* pz = base + (size_t)(j + DIM  ) * DIM + s * 32;
        const float* pn = base + (size_t)(j + 2*DIM) * DIM + s * 32;
        #pragma unroll
        for (int q = 0; q < 8; ++q) {
            float4 v = *(const float4*)(pr + 4 * q);
            wr[4*q+0]=v.x; wr[4*q+1]=v.y; wr[4*q+2]=v.z; wr[4*q+3]=v.w;
        }
        #pragma unroll
        for (int q = 0; q < 8; ++q) {
            float4 v = *(const float4*)(pz + 4 * q);
            wz[4*q+0]=v.x; wz[4*q+1]=v.y; wz[4*q+2]=v.z; wz[4*q+3]=v.w;
        }
        #pragma unroll
        for (int q = 0; q < 8; ++q) {
            float4 v = *(const float4*)(pn + 4 * q);
            wn[4*q+0]=v.x; wn[4*q+1]=v.y; wn[4*q+2]=v.z; wn[4*q+3]=v.w;
        }
    }
    float bhr = bhh[sd * G3 + j];
    float bhz = bhh[sd * G3 + DIM + j];
    float bhn = bhh[sd * G3 + 2 * DIM + j];

    const float* xWp = xW + (size_t)sd * N_NODES * G3;
    const int* mem = members + a * N_NODES;
    int len = lens[a];

    // h ping-pong, slice-padded: slice s at [buf][s][0..31], stride 36 floats
    __shared__ __align__(16) float hbuf[2][4][36];
    for (int i = t0; i < 2 * 4 * 36; i += 512) ((float*)hbuf)[i] = 0.f;
    __syncthreads();

    // prefetch gi for step 0
    int node0 = (len > 0) ? mem[dir ? (len - 1) : 0] : 0;
    float gr = xWp[(size_t)node0 * G3 + j];
    float gz = xWp[(size_t)node0 * G3 + DIM + j];
    float gn = xWp[(size_t)node0 * G3 + 2 * DIM + j];

    int cur = 0;
    for (int t = 0; t < len; ++t) {
        // prefetch next step's gi (overlaps this step's compute + barrier)
        float gr_n = 0.f, gz_n = 0.f, gn_n = 0.f;
        if (t + 1 < len) {
            int nn = mem[dir ? (len - 2 - t) : (t + 1)];
            gr_n = xWp[(size_t)nn * G3 + j];
            gz_n = xWp[(size_t)nn * G3 + DIM + j];
            gn_n = xWp[(size_t)nn * G3 + 2 * DIM + j];
        }
        // partial dots over this thread's 32-wide K slice
        float ar = 0.f, az = 0.f, an_ = 0.f;
        const float4* hp = (const float4*)(&hbuf[cur][s][0]);
        #pragma unroll
        for (int q = 0; q < 8; ++q) {
            float4 hv = hp[q];
            ar = fmaf(wr[4*q+0], hv.x, ar); ar = fmaf(wr[4*q+1], hv.y, ar);
            ar = fmaf(wr[4*q+2], hv.z, ar); ar = fmaf(wr[4*q+3], hv.w, ar);
            az = fmaf(wz[4*q+0], hv.x, az); az = fmaf(wz[4*q+1], hv.y, az);
            az = fmaf(wz[4*q+2], hv.z, az); az = fmaf(wz[4*q+3], hv.w, az);
            an_ = fmaf(wn[4*q+0], hv.x, an_); an_ = fmaf(wn[4*q+1], hv.y, an_);
            an_ = fmaf(wn[4*q+2], hv.z, an_); an_ = fmaf(wn[4*q+3], hv.w, an_);
        }
        // quad reduction (lanes 4j..4j+3 adjacent in wave)
        ar  += __shfl_xor(ar, 1);  ar  += __shfl_xor(ar, 2);
        az  += __shfl_xor(az, 1);  az  += __shfl_xor(az, 2);
        an_ += __shfl_xor(an_, 1); an_ += __shfl_xor(an_, 2);

        float r  = fast_sigmoid(gr + ar + bhr);
        float z  = fast_sigmoid(gz + az + bhz);
        float nv = fast_tanh(gn + r * (an_ + bhn));
        float hj = hbuf[cur][j >> 5][j & 31];     // LDS re-read: keeps live set at 64 VGPR
        float hnew = (1.f - z) * nv + z * hj;
        if (s == 0) hbuf[cur ^ 1][j >> 5][j & 31] = hnew;
        __syncthreads();
        cur ^= 1;
        gr = gr_n; gz = gz_n; gn = gn_n;
    }
    if (s == 0) feat_out[a * 256 + dir * DIM + j] = hbuf[cur][j >> 5][j & 31];
}

// ============ Kernel 3: per-anchor MLP head + boundary refinement ============
__global__ __launch_bounds__(256) void head_kernel(
    const float* __restrict__ feat, const float* __restrict__ abn_res,
    const float* __restrict__ anchors, const float* __restrict__ alp,
    const float* __restrict__ W1, const float* __restrict__ b1,
    const float* __restrict__ W2, const float* __restrict__ b2,
    const float* __restrict__ W3, const float* __restrict__ b3,
    const float* __restrict__ sw, const float* __restrict__ ew,
    float* __restrict__ out)
{
    int a = blockIdx.x;
    int tid = threadIdx.x;   // 0..255
    int s = a >> 6;
    __shared__ float sf[260];
    __shared__ float h1[256];
    __shared__ float h2[256];
    __shared__ float o[FOUT];
    float al = alp[0];
    float st = anchors[a * 2 + 0];
    float en = anchors[a * 2 + 1];
    sf[tid] = feat[a * 256 + tid];
    if (tid == 0) {
        sf[256] = abn_res[a];
        sf[257] = (st + en) * 0.5f / al;
        sf[258] = (en - st) / al;
    }
    __syncthreads();

    const float* w1 = W1 + (size_t)s * 259 * 256;
    float acc = b1[s * 256 + tid];
    for (int jj = 0; jj < 259; ++jj) acc = fmaf(sf[jj], w1[jj * 256 + tid], acc);
    h1[tid] = fmaxf(acc, 0.f);
    __syncthreads();

    const float* w2 = W2 + (size_t)s * 256 * 256;
    acc = b2[s * 256 + tid];
    for (int jj = 0; jj < 256; ++jj) acc = fmaf(h1[jj], w2[jj * 256 + tid], acc);
    h2[tid] = fmaxf(acc, 0.f);
    __syncthreads();

    if (tid < FOUT) {
        const float* w3 = W3 + (size_t)s * 256 * FOUT;
        acc = b3[s * FOUT + tid];
        for (int jj = 0; jj < 256; ++jj) acc = fmaf(h2[jj], w3[jj * FOUT + tid], acc);
        o[tid] = acc;
    }
    __syncthreads();

    if (tid < 2) {   // tid 0: start offset, tid 1: end offset
        const float* lw = (tid == 0) ? (sw + s * DBINS) : (ew + s * DBINS);
        const float* sl = o + tid * DBINS;
        float m = sl[0];
        for (int jj = 1; jj < DBINS; ++jj) m = fmaxf(m, sl[jj]);
        float sum = 0.f, dot = 0.f;
        for (int jj = 0; jj < DBINS; ++jj) {
            float e = __expf(sl[jj] - m);
            sum += e;
            dot = fmaf(e, lw[jj], dot);
        }
        float off = dot / sum;
        float base = (tid == 0) ? st : en;
        out[a * 2 + tid] = fminf(fmaxf(base + off, 0.f), al);
    }
    if (tid == 42) out[2 * NANCH + a] = o[42];                           // conf
    if (tid >= 43 && tid < FOUT) out[3 * NANCH + a * 4 + (tid - 43)] = o[tid]; // cls
}

extern "C" void kernel_launch(void* const* d_in, const int* in_sizes, int n_in,
                              void* d_out, int out_size, void* d_ws, size_t ws_size,
                              hipStream_t stream) {
    const float* emb   = (const float*)d_in[0];
    const float* tpin  = (const float*)d_in[1];
    const float* npred = (const float*)d_in[2];
    const float* alp   = (const float*)d_in[3];
    const float* anch  = (const float*)d_in[4];
    const float* skern = (const float*)d_in[5];
    const float* fWih  = (const float*)d_in[6];
    const float* fWhh  = (const float*)d_in[7];
    const float* fbih  = (const float*)d_in[8];
    const float* fbhh  = (const float*)d_in[9];
    const float* aWih  = (const float*)d_in[10];
    const float* aWhh  = (const float*)d_in[11];
    const float* abih  = (const float*)d_in[12];
    const float* abhh  = (const float*)d_in[13];
    const float* sw    = (const float*)d_in[14];
    const float* ew    = (const float*)d_in[15];
    const float* W1    = (const float*)d_in[16];
    const float* b1    = (const float*)d_in[17];
    const float* W2    = (const float*)d_in[18];
    const float* b2    = (const float*)d_in[19];
    const float* W3    = (const float*)d_in[20];
    const float* b3    = (const float*)d_in[21];

    float* ws = (float*)d_ws;
    float* xW       = ws;                      // 6*512*384 = 1179648
    float* abn_res  = ws + 1179648;            // 192 (pad 256)
    float* feat     = ws + 1179904;            // 192*256 = 49152
    int*   members  = (int*)(ws + 1229056);    // 192*512 ints = 98304
    int*   lens     = (int*)(ws + 1327360);    // 192 ints
    float* outp     = (float*)d_out;

    prep_kernel<<<384, 384, 0, stream>>>(emb, tpin, fWih, fbih, alp, anch, npred, skern,
                                         aWih, aWhh, abih, abhh,
                                         xW, members, lens, abn_res);
    gru_feat_kernel<<<2 * NANCH, 512, 0, stream>>>(xW, fWhh, fbhh, members, lens, anch, feat);
    head_kernel<<<NANCH, 256, 0, stream>>>(feat, abn_res, anch, alp,
                                           W1, b1, W2, b2, W3, b3, sw, ew, outp);
}